// Round 1
// baseline (591.328 us; speedup 1.0000x reference)
//
#include <hip/hip_runtime.h>

// Problem constants (from reference)
#define H_ 4
#define B_ 16
#define T_ 4000
#define E_ 512
#define D_ 512
#define A_ 128
#define C_ 10
#define K_ 101
#define O_ 512

#define TC_ 50          // context T-chunks
#define CH_ (T_ / TC_)  // 80

__device__ __forceinline__ float tanh_fast(float x) {
    // tanh(x) = 1 - 2/(exp(2x)+1); __expf handles +-inf limits correctly
    return 1.0f - 2.0f / (__expf(2.0f * x) + 1.0f);
}

// ---------------------------------------------------------------------------
// dec_proj[b,h,a] = sum_d dec_z[b,d] * Wdec[h,d,a]
__global__ __launch_bounds__(128) void k_decproj(const float* __restrict__ dec_z,
                                                 const float* __restrict__ Wdec,
                                                 float* __restrict__ decp) {
    const int b = blockIdx.x / H_, h = blockIdx.x % H_;
    const int a = threadIdx.x;
    const float* wz = Wdec + (size_t)h * D_ * A_ + a;
    const float* z  = dec_z + (size_t)b * D_;
    float s = 0.f;
#pragma unroll 8
    for (int d = 0; d < D_; ++d) s += z[d] * wz[(size_t)d * A_];
    decp[(b * H_ + h) * A_ + a] = s;
}

// ---------------------------------------------------------------------------
// conv[b,t,h,c] = sum_k att_prev[h,b,t+k-50] * conv_w[h,c,k]   (zero padded)
__global__ __launch_bounds__(256) void k_conv(const float* __restrict__ att_prev,
                                              const float* __restrict__ conv_w,
                                              float* __restrict__ convb) {
    const int bh = blockIdx.x;
    const int b = bh / H_, h = bh % H_;
    const int t0 = blockIdx.y * 256;
    __shared__ float ap[256 + K_ - 1 + 3];
    __shared__ float cw[C_ * K_];
    const float* src = att_prev + ((size_t)h * B_ + b) * T_;
    for (int i = threadIdx.x; i < 256 + K_ - 1; i += 256) {
        int tt = t0 - (K_ / 2) + i;
        ap[i] = (tt >= 0 && tt < T_) ? src[tt] : 0.f;
    }
    for (int i = threadIdx.x; i < C_ * K_; i += 256) cw[i] = conv_w[(size_t)h * C_ * K_ + i];
    __syncthreads();
    const int t = t0 + threadIdx.x;
    if (t < T_) {
        float s[C_];
#pragma unroll
        for (int c = 0; c < C_; ++c) s[c] = 0.f;
        for (int k = 0; k < K_; ++k) {
            float apv = ap[threadIdx.x + k];
#pragma unroll
            for (int c = 0; c < C_; ++c) s[c] += cw[c * K_ + k] * apv;
        }
        float* dst = convb + (((size_t)b * T_ + t) * H_ + h) * C_;
#pragma unroll
        for (int c = 0; c < C_; ++c) dst[c] = s[c];
    }
}

// ---------------------------------------------------------------------------
// Fused: e[b,h,t] = sum_a gv[h,a]*tanh( enc_pad[b,t,:] @ Wenc[h,:,a] + benc[h,a]
//                                       + dec_proj[b,h,a] + att_conv[b,h,t,a] )
// GEMM: M=64000 (b*T+t), N=128 (a, per head), K=512. Tile 128x128, Kstep 16.
__global__ __launch_bounds__(256) void k_fused_e(
    const float* __restrict__ enc,
    const float* __restrict__ Wenc,
    const float* __restrict__ benc,
    const float* __restrict__ decp,
    const float* __restrict__ convb,
    const float* __restrict__ Watt,
    const float* __restrict__ gv,
    float* __restrict__ e_out) {
    const int h  = blockIdx.x;
    const int m0 = blockIdx.y * 128;
    const int tid = threadIdx.x;
    const int tx = tid & 15, ty = tid >> 4;

    __shared__ float As[16][132];   // [k][row], pad to 132 -> <=2-way write conflicts
    __shared__ float Bs[16][128];   // [k][col]
    __shared__ float WattS[C_][A_];
    __shared__ float gvS[A_];

    for (int i = tid; i < C_ * A_; i += 256) WattS[i / A_][i % A_] = Watt[(size_t)h * C_ * A_ + i];
    if (tid < A_) gvS[tid] = gv[h * A_ + tid];

    float acc[8][8];
#pragma unroll
    for (int i = 0; i < 8; ++i)
#pragma unroll
        for (int j = 0; j < 8; ++j) acc[i][j] = 0.f;

    const float* Wh = Wenc + (size_t)h * E_ * A_;

    for (int kt = 0; kt < E_ / 16; ++kt) {
        const int k0 = kt * 16;
        __syncthreads();
        // stage A: 128 rows x 16 k (transposed into As[k][row])
#pragma unroll
        for (int q = 0; q < 2; ++q) {
            int i = tid + q * 256;
            int row = i >> 2, kc = i & 3;
            const float4 f = *reinterpret_cast<const float4*>(
                &enc[(size_t)(m0 + row) * E_ + k0 + kc * 4]);
            As[kc * 4 + 0][row] = f.x;
            As[kc * 4 + 1][row] = f.y;
            As[kc * 4 + 2][row] = f.z;
            As[kc * 4 + 3][row] = f.w;
        }
        // stage B: 16 k x 128 cols
#pragma unroll
        for (int q = 0; q < 2; ++q) {
            int i = tid + q * 256;
            int kk = i >> 5, c4 = i & 31;
            const float4 f = *reinterpret_cast<const float4*>(
                &Wh[(size_t)(k0 + kk) * A_ + c4 * 4]);
            *reinterpret_cast<float4*>(&Bs[kk][c4 * 4]) = f;
        }
        __syncthreads();
#pragma unroll
        for (int kk = 0; kk < 16; ++kk) {
            const float4 a0 = *reinterpret_cast<const float4*>(&As[kk][ty * 8]);
            const float4 a1 = *reinterpret_cast<const float4*>(&As[kk][ty * 8 + 4]);
            const float4 b0 = *reinterpret_cast<const float4*>(&Bs[kk][tx * 8]);
            const float4 b1 = *reinterpret_cast<const float4*>(&Bs[kk][tx * 8 + 4]);
            const float av[8] = {a0.x, a0.y, a0.z, a0.w, a1.x, a1.y, a1.z, a1.w};
            const float bv[8] = {b0.x, b0.y, b0.z, b0.w, b1.x, b1.y, b1.z, b1.w};
#pragma unroll
            for (int i = 0; i < 8; ++i)
#pragma unroll
                for (int j = 0; j < 8; ++j) acc[i][j] += av[i] * bv[j];
        }
    }

    // Epilogue: add benc + dec_proj + att_conv, tanh, dot with gv, reduce over cols
    const float* bh_benc = benc + h * A_;
#pragma unroll
    for (int i = 0; i < 8; ++i) {
        const int row = m0 + ty * 8 + i;
        const int b = row / T_, t = row % T_;
        const float* cv = &convb[((size_t)row * H_ + h) * C_];
        float cvr[C_];
#pragma unroll
        for (int c = 0; c < C_; ++c) cvr[c] = cv[c];
        const float* dp = decp + (b * H_ + h) * A_;
        float psum = 0.f;
#pragma unroll
        for (int j = 0; j < 8; ++j) {
            const int col = tx * 8 + j;
            float s = acc[i][j] + bh_benc[col] + dp[col];
#pragma unroll
            for (int c = 0; c < C_; ++c) s += cvr[c] * WattS[c][col];
            psum += gvS[col] * tanh_fast(s);
        }
#pragma unroll
        for (int off = 1; off < 16; off <<= 1) psum += __shfl_xor(psum, off, 16);
        if (tx == 0) e_out[((size_t)b * H_ + h) * T_ + t] = psum;
    }
}

// ---------------------------------------------------------------------------
// softmax over T per (b,h); writes ws output directly in [H,B,T] layout
__global__ __launch_bounds__(256) void k_softmax(const float* __restrict__ e_in,
                                                 float* __restrict__ wout) {
    const int b = blockIdx.x / H_, h = blockIdx.x % H_;
    const float* er = e_in + ((size_t)b * H_ + h) * T_;
    __shared__ float red[256];
    const int tid = threadIdx.x;
    float m = -1e30f;
    for (int t = tid; t < T_; t += 256) m = fmaxf(m, er[t]);
    red[tid] = m;
    __syncthreads();
    for (int s = 128; s > 0; s >>= 1) {
        if (tid < s) red[tid] = fmaxf(red[tid], red[tid + s]);
        __syncthreads();
    }
    m = red[0];
    __syncthreads();
    float sum = 0.f;
    for (int t = tid; t < T_; t += 256) sum += __expf(er[t] - m);
    red[tid] = sum;
    __syncthreads();
    for (int s = 128; s > 0; s >>= 1) {
        if (tid < s) red[tid] += red[tid + s];
        __syncthreads();
    }
    const float inv = 1.0f / red[0];
    float* dst = wout + ((size_t)h * B_ + b) * T_;
    for (int t = tid; t < T_; t += 256) dst[t] = __expf(er[t] - m) * inv;
}

// ---------------------------------------------------------------------------
// context partials: partial[tc,b,h,e] = sum_{t in chunk} w[h,b,t]*enc[b,t,e]
__global__ __launch_bounds__(512) void k_ctx(const float* __restrict__ enc,
                                             const float* __restrict__ wsrc,
                                             float* __restrict__ partial) {
    const int b = blockIdx.x, tc = blockIdx.y;
    const int tid = threadIdx.x;
    __shared__ float wls[H_ * CH_];
    const int t0 = tc * CH_;
    for (int i = tid; i < H_ * CH_; i += 512) {
        int hh = i / CH_, tt = i % CH_;
        wls[i] = wsrc[((size_t)hh * B_ + b) * T_ + t0 + tt];
    }
    __syncthreads();
    float a0 = 0.f, a1 = 0.f, a2 = 0.f, a3 = 0.f;
    const float* ebase = enc + ((size_t)b * T_ + t0) * E_ + tid;
#pragma unroll 4
    for (int tt = 0; tt < CH_; ++tt) {
        float x = ebase[(size_t)tt * E_];
        a0 += wls[tt] * x;
        a1 += wls[CH_ + tt] * x;
        a2 += wls[2 * CH_ + tt] * x;
        a3 += wls[3 * CH_ + tt] * x;
    }
    float* pdst = partial + (((size_t)tc * B_ + b) * H_) * E_ + tid;
    pdst[0] = a0;
    pdst[E_] = a1;
    pdst[2 * E_] = a2;
    pdst[3 * E_] = a3;
}

__global__ __launch_bounds__(256) void k_reduce_c(const float* __restrict__ partial,
                                                  float* __restrict__ c) {
    const int i = blockIdx.x * 256 + threadIdx.x;  // < B*H*E = 32768
    float s = 0.f;
#pragma unroll
    for (int tc = 0; tc < TC_; ++tc) s += partial[(size_t)tc * (B_ * H_ * E_) + i];
    c[i] = s;
}

// ---------------------------------------------------------------------------
// out[b,o] = bo[o] + sum_he c[b,he] * Wo[he,o]  (split-K over 8 chunks)
__global__ __launch_bounds__(256) void k_out_part(const float* __restrict__ c,
                                                  const float* __restrict__ Wo,
                                                  float* __restrict__ p2) {
    const int b = blockIdx.x;
    const int o = blockIdx.y * 256 + threadIdx.x;
    const int kc = blockIdx.z;
    __shared__ float cS[256];
    const int he0 = kc * 256;
    cS[threadIdx.x] = c[b * (H_ * E_) + he0 + threadIdx.x];
    __syncthreads();
    float s = 0.f;
#pragma unroll 8
    for (int i = 0; i < 256; ++i) s += cS[i] * Wo[(size_t)(he0 + i) * O_ + o];
    p2[((size_t)kc * B_ + b) * O_ + o] = s;
}

__global__ __launch_bounds__(512) void k_out_fin(const float* __restrict__ p2,
                                                 const float* __restrict__ bo,
                                                 float* __restrict__ out) {
    const int b = blockIdx.x, o = threadIdx.x;
    float s = bo[o];
#pragma unroll
    for (int kc = 0; kc < 8; ++kc) s += p2[((size_t)kc * B_ + b) * O_ + o];
    out[b * O_ + o] = s;
}

// ---------------------------------------------------------------------------
extern "C" void kernel_launch(void* const* d_in, const int* in_sizes, int n_in,
                              void* d_out, int out_size, void* d_ws, size_t ws_size,
                              hipStream_t stream) {
    (void)in_sizes; (void)n_in; (void)out_size; (void)ws_size;
    const float* enc      = (const float*)d_in[0];
    // d_in[1] = enc_len : unused by the reference
    const float* dec_z    = (const float*)d_in[2];
    const float* att_prev = (const float*)d_in[3];
    const float* Wenc     = (const float*)d_in[4];
    const float* benc     = (const float*)d_in[5];
    const float* Wdec     = (const float*)d_in[6];
    const float* Watt     = (const float*)d_in[7];
    const float* conv_w   = (const float*)d_in[8];
    const float* gv       = (const float*)d_in[9];
    const float* Wo       = (const float*)d_in[10];
    const float* bo       = (const float*)d_in[11];

    float* out  = (float*)d_out;        // [B,O]
    float* wout = out + B_ * O_;        // ws [H,B,T]

    // workspace layout (floats)
    float* ws      = (float*)d_ws;
    float* e_buf   = ws;                                   // B*H*T      = 256000
    float* convb   = e_buf + (size_t)B_ * H_ * T_;         // B*T*H*C    = 2,560,000
    float* decp    = convb + (size_t)B_ * T_ * H_ * C_;    // B*H*A      = 8192
    float* partial = decp + B_ * H_ * A_;                  // TC*B*H*E   = 1,638,400
    float* cbuf    = partial + (size_t)TC_ * B_ * H_ * E_; // B*H*E      = 32768
    float* p2      = cbuf + B_ * H_ * E_;                  // 8*B*O      = 65536

    hipLaunchKernelGGL(k_decproj, dim3(B_ * H_), dim3(128), 0, stream, dec_z, Wdec, decp);
    hipLaunchKernelGGL(k_conv, dim3(B_ * H_, (T_ + 255) / 256), dim3(256), 0, stream,
                       att_prev, conv_w, convb);
    hipLaunchKernelGGL(k_fused_e, dim3(H_, (B_ * T_) / 128), dim3(256), 0, stream,
                       enc, Wenc, benc, decp, convb, Watt, gv, e_buf);
    hipLaunchKernelGGL(k_softmax, dim3(B_ * H_), dim3(256), 0, stream, e_buf, wout);
    hipLaunchKernelGGL(k_ctx, dim3(B_, TC_), dim3(512), 0, stream, enc, wout, partial);
    hipLaunchKernelGGL(k_reduce_c, dim3(B_ * H_ * E_ / 256), dim3(256), 0, stream, partial, cbuf);
    hipLaunchKernelGGL(k_out_part, dim3(B_, O_ / 256, 8), dim3(256), 0, stream, cbuf, Wo, p2);
    hipLaunchKernelGGL(k_out_fin, dim3(B_), dim3(512), 0, stream, p2, bo, out);
}

// Round 2
// 167.690 us; speedup vs baseline: 3.5263x; 3.5263x over previous
//
#include <hip/hip_runtime.h>

#define H_ 4
#define B_ 16
#define T_ 4000
#define E_ 512
#define D_ 512
#define A_ 128
#define C_ 10
#define K_ 101
#define O_ 512
#define TC_ 50
#define CH_ (T_ / TC_)

typedef __attribute__((ext_vector_type(16))) float f32x16;
typedef __attribute__((ext_vector_type(8)))  short short8;

#define MFMA32(a, b, c) __builtin_amdgcn_mfma_f32_32x32x16_bf16(a, b, c, 0, 0, 0)

#define GLL16(gp, lp) __builtin_amdgcn_global_load_lds( \
    (const __attribute__((address_space(1))) unsigned int*)(gp), \
    (__attribute__((address_space(3))) unsigned int*)(lp), 16, 0, 0)

static __device__ __forceinline__ unsigned short f2bf(float x) {
  unsigned u = __float_as_uint(x);
  unsigned r = (u + 0x7FFFu + ((u >> 16) & 1u)) >> 16;
  return (unsigned short)r;
}
static __device__ __forceinline__ unsigned pk2(float a, float b) {
  return (unsigned)f2bf(a) | ((unsigned)f2bf(b) << 16);
}
static __device__ __forceinline__ uint4 packbf8(float4 f0, float4 f1) {
  uint4 u;
  u.x = pk2(f0.x, f0.y); u.y = pk2(f0.z, f0.w);
  u.z = pk2(f1.x, f1.y); u.w = pk2(f1.z, f1.w);
  return u;
}
static __device__ __forceinline__ f32x16 zero16() {
  f32x16 z;
#pragma unroll
  for (int i = 0; i < 16; ++i) z[i] = 0.f;
  return z;
}
static __device__ __forceinline__ float tanh_fast(float x) {
  // correct limits: x->+inf => 1, x->-inf => -1
  return 1.0f - 2.0f / (__expf(2.0f * x) + 1.0f);
}
// swizzled byte offset for 32-k-wide bf16 tiles packed as 2 rows per 128B line
static __device__ __forceinline__ int swz32(int r, int ksg) {
  return (r >> 1) * 128 + (((((r & 1) << 2) | ksg) ^ ((r >> 1) & 7)) << 4);
}
// swizzled byte offset for 64-elem-wide bf16 rows (128B per row)
static __device__ __forceinline__ int swzC(int r, int sl) {
  return r * 128 + ((sl ^ (r & 7)) << 4);
}

// ---------------------------------------------------------------------------
// addv[b,h,a] = benc[h,a] + sum_d dec_z[b,d] * Wdec[h,d,a]
__global__ __launch_bounds__(128) void k_addv(const float* __restrict__ dec_z,
                                              const float* __restrict__ Wdec,
                                              const float* __restrict__ benc,
                                              float* __restrict__ addv) {
  const int b = blockIdx.x / H_, h = blockIdx.x % H_;
  const int a = threadIdx.x;
  const float* wz = Wdec + (size_t)h * D_ * A_ + a;
  const float* z  = dec_z + (size_t)b * D_;
  float s = benc[h * A_ + a];
#pragma unroll 8
  for (int d = 0; d < D_; ++d) s += z[d] * wz[(size_t)d * A_];
  addv[(b * H_ + h) * A_ + a] = s;
}

// ---------------------------------------------------------------------------
// conv features, bf16, padded: convpad[row=b*T+t][h*16 + c], c in [0,16), c>=10 -> 0
__global__ __launch_bounds__(256) void k_conv(const float* __restrict__ att_prev,
                                              const float* __restrict__ conv_w,
                                              char* __restrict__ convpad) {
  const int bh = blockIdx.x;
  const int b = bh / H_, h = bh % H_;
  const int t0 = blockIdx.y * 256;
  __shared__ float ap[256 + K_ - 1 + 3];
  __shared__ float cw[C_ * K_];
  const float* src = att_prev + ((size_t)h * B_ + b) * T_;
  for (int i = threadIdx.x; i < 256 + K_ - 1; i += 256) {
    int tt = t0 - (K_ / 2) + i;
    ap[i] = (tt >= 0 && tt < T_) ? src[tt] : 0.f;
  }
  for (int i = threadIdx.x; i < C_ * K_; i += 256) cw[i] = conv_w[(size_t)h * C_ * K_ + i];
  __syncthreads();
  const int t = t0 + threadIdx.x;
  if (t < T_) {
    float s[C_];
#pragma unroll
    for (int c = 0; c < C_; ++c) s[c] = 0.f;
    for (int k = 0; k < K_; ++k) {
      float apv = ap[threadIdx.x + k];
#pragma unroll
      for (int c = 0; c < C_; ++c) s[c] += cw[c * K_ + k] * apv;
    }
    uint4 u0, u1;
    u0.x = pk2(s[0], s[1]); u0.y = pk2(s[2], s[3]);
    u0.z = pk2(s[4], s[5]); u0.w = pk2(s[6], s[7]);
    u1.x = pk2(s[8], s[9]); u1.y = 0u; u1.z = 0u; u1.w = 0u;
    char* dst = convpad + (size_t)(b * T_ + t) * 128 + h * 32;
    *(uint4*)dst = u0;
    *(uint4*)(dst + 16) = u1;
  }
}

// ---------------------------------------------------------------------------
// Pre-swizzled bf16 operand buffers for the MFMA GEMM:
//  wbs:   [16 kt][n=512][k=32] with double-row XOR swizzle (16 x 32KB)
//  wattb: [h][a=128][k=16] padded Watt, 4-col/128B-line XOR swizzle (16KB)
__global__ __launch_bounds__(256) void k_wprep(const float* __restrict__ Wenc,
                                               const float* __restrict__ Watt,
                                               char* __restrict__ wbs,
                                               char* __restrict__ wattb) {
  const int c = blockIdx.x * 256 + threadIdx.x;
  if (c < 32768) {
    const int cc = c & 2047;
    const int kt = c >> 11;
    const int line = cc >> 3, sp = cc & 7;
    const int sraw = sp ^ (line & 7);
    const int n = line * 2 + (sraw >> 2);
    const int ksg = sraw & 3;
    const int h = n >> 7, a = n & 127;
    const int kb = kt * 32 + ksg * 8;
    uint4 u;
    u.x = pk2(Wenc[((size_t)h * E_ + kb + 0) * A_ + a], Wenc[((size_t)h * E_ + kb + 1) * A_ + a]);
    u.y = pk2(Wenc[((size_t)h * E_ + kb + 2) * A_ + a], Wenc[((size_t)h * E_ + kb + 3) * A_ + a]);
    u.z = pk2(Wenc[((size_t)h * E_ + kb + 4) * A_ + a], Wenc[((size_t)h * E_ + kb + 5) * A_ + a]);
    u.w = pk2(Wenc[((size_t)h * E_ + kb + 6) * A_ + a], Wenc[((size_t)h * E_ + kb + 7) * A_ + a]);
    ((uint4*)wbs)[c] = u;
  } else if (c < 32768 + 1024) {
    const int cw = c - 32768;
    const int h = cw >> 8, cc = cw & 255;
    const int line = cc >> 3, sp = cc & 7;
    const int sraw = sp ^ (line & 7);
    const int a = line * 4 + (sraw >> 1);
    const int s = sraw & 1;
    unsigned short v[8];
#pragma unroll
    for (int j = 0; j < 8; ++j) {
      const int k = s * 8 + j;
      v[j] = (k < C_) ? f2bf(Watt[((size_t)h * C_ + k) * A_ + a]) : (unsigned short)0;
    }
    uint4 u;
    u.x = (unsigned)v[0] | ((unsigned)v[1] << 16);
    u.y = (unsigned)v[2] | ((unsigned)v[3] << 16);
    u.z = (unsigned)v[4] | ((unsigned)v[5] << 16);
    u.w = (unsigned)v[6] | ((unsigned)v[7] << 16);
    ((uint4*)wattb)[cw] = u;
  }
}

// ---------------------------------------------------------------------------
// Fused MFMA kernel: e[b,h,t] = sum_a gv[h,a]*tanh( enc@Wenc + conv@Watt + addv )
// Block: 64 rows x 512 cols (4 waves = 4 heads), BK=32, 16 K-tiles + conv tile.
__global__ __launch_bounds__(256, 2) void k_fused_e_mfma(
    const float* __restrict__ enc,
    const char*  __restrict__ wbs,
    const char*  __restrict__ convpad,
    const char*  __restrict__ wattb,
    const float* __restrict__ addv,
    const float* __restrict__ gv,
    float* __restrict__ e_out) {
  __shared__ char smem[73728];
  const int ABUF0o = 0, ABUF1o = 4096, BBUF0o = 8192, BBUF1o = 40960;
  const int tid = threadIdx.x;
  const int wh = tid >> 6;     // wave == head
  const int lane = tid & 63;
  const int ln31 = lane & 31;
  const int hi = lane >> 5;
  const int m0 = blockIdx.x * 64;
  const unsigned b0 = (unsigned)m0 / 4000u;
  const unsigned b1 = (unsigned)(m0 + 63) / 4000u;

  f32x16 acc[2][4];
#pragma unroll
  for (int i = 0; i < 2; ++i)
#pragma unroll
    for (int j = 0; j < 4; ++j) acc[i][j] = zero16();

  // staging geometry (constant per thread)
  const int srow = tid >> 2, sksg = tid & 3;
  const int stA = swz32(srow, sksg);
  const float* encRow = enc + (size_t)(m0 + srow) * E_ + sksg * 8;
  const int wbase = (tid >> 6) * 1024;
  const int lof = (tid & 63) * 16;

  // ---- prologue: stage K-tile 0
  {
    float4 f0 = ((const float4*)encRow)[0];
    float4 f1 = ((const float4*)encRow)[1];
    *(uint4*)(smem + ABUF0o + stA) = packbf8(f0, f1);
#pragma unroll
    for (int it = 0; it < 8; ++it)
      GLL16(wbs + (size_t)it * 4096 + wbase + lof, smem + BBUF0o + it * 4096 + wbase);
  }
  __syncthreads();

  for (int kt = 0; kt < 16; ++kt) {
    const int cur = kt & 1;
    const char* Ab = smem + (cur ? ABUF1o : ABUF0o);
    const char* Bb = smem + (cur ? BBUF1o : BBUF0o);
    char* An = smem + (cur ? ABUF0o : ABUF1o);
    char* Bn = smem + (cur ? BBUF0o : BBUF1o);

    uint4 pk = {0, 0, 0, 0};
    uint4 rc0 = {0, 0, 0, 0}, rc1 = {0, 0, 0, 0};
    float av00 = 0.f, av01 = 0.f, av10 = 0.f, av11 = 0.f, g0 = 0.f, g1 = 0.f;

    if (kt < 15) {
      const float* apk = encRow + (kt + 1) * 32;
      float4 f0 = ((const float4*)apk)[0];
      float4 f1 = ((const float4*)apk)[1];
      pk = packbf8(f0, f1);
#pragma unroll
      for (int it = 0; it < 8; ++it)
        GLL16(wbs + (size_t)(kt + 1) * 32768 + it * 4096 + wbase + lof,
              Bn + it * 4096 + wbase);
    } else {
      // stage conv A (8KB), Watt B (16KB), addv (4KB), gv (2KB) into buffers 0
      rc0 = *(const uint4*)(convpad + (size_t)(m0 + (tid >> 3)) * 128 + (tid & 7) * 16);
      rc1 = *(const uint4*)(convpad + (size_t)(m0 + ((tid + 256) >> 3)) * 128 + (tid & 7) * 16);
#pragma unroll
      for (int it = 0; it < 4; ++it)
        GLL16(wattb + (size_t)it * 4096 + wbase + lof, Bn + 8192 + it * 4096 + wbase);
      av00 = addv[b0 * 512 + tid];
      av01 = addv[b0 * 512 + 256 + tid];
      av10 = addv[b1 * 512 + tid];
      av11 = addv[b1 * 512 + 256 + tid];
      g0 = gv[tid]; g1 = gv[tid + 256];
    }

    // ---- compute on current buffers
#pragma unroll
    for (int kc = 0; kc < 2; ++kc) {
      const int ksg = kc * 2 + hi;
      short8 a0 = *(const short8*)(Ab + swz32(ln31, ksg));
      short8 a1 = *(const short8*)(Ab + swz32(32 + ln31, ksg));
#pragma unroll
      for (int ni = 0; ni < 4; ++ni) {
        const int n = wh * 128 + ni * 32 + ln31;
        short8 bfr = *(const short8*)(Bb + swz32(n, ksg));
        acc[0][ni] = MFMA32(a0, bfr, acc[0][ni]);
        acc[1][ni] = MFMA32(a1, bfr, acc[1][ni]);
      }
    }

    if (kt < 15) {
      *(uint4*)(An + stA) = pk;
    } else {
      const int r0 = tid >> 3, s0 = tid & 7;
      *(uint4*)(Bn + swzC(r0, s0)) = rc0;
      const int r1 = (tid + 256) >> 3;
      *(uint4*)(Bn + swzC(r1, s0)) = rc1;
      ((float*)An)[tid] = av00;
      ((float*)An)[tid + 256] = av01;
      ((float*)An)[tid + 512] = av10;
      ((float*)An)[tid + 768] = av11;
      ((float*)(Bn + 24576))[tid] = g0;
      ((float*)(Bn + 24576))[tid + 256] = g1;
    }
    __syncthreads();
  }

  // ---- conv MFMA step (K=16): A = conv features, B = Watt
  {
    const char* AconvL = smem + BBUF0o;
    const char* WattL  = smem + BBUF0o + 8192;
    const int sl = wh * 2 + hi;
    short8 ac0 = *(const short8*)(AconvL + swzC(ln31, sl));
    short8 ac1 = *(const short8*)(AconvL + swzC(32 + ln31, sl));
#pragma unroll
    for (int ni = 0; ni < 4; ++ni) {
      const int a = ni * 32 + ln31;
      short8 wf = *(const short8*)(WattL + wh * 4096 + (a >> 2) * 128 +
                                   (((((a & 3) << 1) | hi) ^ ((a >> 2) & 7)) << 4));
      acc[0][ni] = MFMA32(ac0, wf, acc[0][ni]);
      acc[1][ni] = MFMA32(ac1, wf, acc[1][ni]);
    }
  }

  // ---- epilogue: + addv, tanh, dot gv, reduce over cols, store e
  {
    const float* addvL = (const float*)(smem + ABUF0o);
    const float* gvS   = (const float*)(smem + BBUF0o + 24576);
    float av0[4], av1[4], gvr[4];
#pragma unroll
    for (int ni = 0; ni < 4; ++ni) {
      const int a = wh * 128 + ni * 32 + ln31;
      av0[ni] = addvL[a];
      av1[ni] = addvL[512 + a];
      gvr[ni] = gvS[a];
    }
#pragma unroll
    for (int mi = 0; mi < 2; ++mi) {
#pragma unroll
      for (int reg = 0; reg < 16; ++reg) {
        const int rl = mi * 32 + (reg & 3) + ((reg >> 2) << 3) + (hi << 2);
        const unsigned brow = (unsigned)(m0 + rl);
        const unsigned bb = brow / 4000u;
        const unsigned tt = brow - bb * 4000u;
        const int sel = (bb != b0);
        float rs = 0.f;
#pragma unroll
        for (int ni = 0; ni < 4; ++ni) {
          float s = acc[mi][ni][reg] + (sel ? av1[ni] : av0[ni]);
          rs += gvr[ni] * tanh_fast(s);
        }
        rs += __shfl_xor(rs, 1);
        rs += __shfl_xor(rs, 2);
        rs += __shfl_xor(rs, 4);
        rs += __shfl_xor(rs, 8);
        rs += __shfl_xor(rs, 16);
        if (ln31 == 0) e_out[((size_t)bb * H_ + wh) * T_ + tt] = rs;
      }
    }
  }
}

// ---------------------------------------------------------------------------
__global__ __launch_bounds__(256) void k_softmax(const float* __restrict__ e_in,
                                                 float* __restrict__ wout) {
  const int b = blockIdx.x / H_, h = blockIdx.x % H_;
  const float* er = e_in + ((size_t)b * H_ + h) * T_;
  __shared__ float red[256];
  const int tid = threadIdx.x;
  float m = -1e30f;
  for (int t = tid; t < T_; t += 256) m = fmaxf(m, er[t]);
  red[tid] = m;
  __syncthreads();
  for (int s = 128; s > 0; s >>= 1) {
    if (tid < s) red[tid] = fmaxf(red[tid], red[tid + s]);
    __syncthreads();
  }
  m = red[0];
  __syncthreads();
  float sum = 0.f;
  for (int t = tid; t < T_; t += 256) sum += __expf(er[t] - m);
  red[tid] = sum;
  __syncthreads();
  for (int s = 128; s > 0; s >>= 1) {
    if (tid < s) red[tid] += red[tid + s];
    __syncthreads();
  }
  const float inv = 1.0f / red[0];
  float* dst = wout + ((size_t)h * B_ + b) * T_;
  for (int t = tid; t < T_; t += 256) dst[t] = __expf(er[t] - m) * inv;
}

// ---------------------------------------------------------------------------
__global__ __launch_bounds__(512) void k_ctx(const float* __restrict__ enc,
                                             const float* __restrict__ wsrc,
                                             float* __restrict__ partial) {
  const int b = blockIdx.x, tc = blockIdx.y;
  const int tid = threadIdx.x;
  __shared__ float wls[H_ * CH_];
  const int t0 = tc * CH_;
  for (int i = tid; i < H_ * CH_; i += 512) {
    int hh = i / CH_, tt = i % CH_;
    wls[i] = wsrc[((size_t)hh * B_ + b) * T_ + t0 + tt];
  }
  __syncthreads();
  float a0 = 0.f, a1 = 0.f, a2 = 0.f, a3 = 0.f;
  const float* ebase = enc + ((size_t)b * T_ + t0) * E_ + tid;
#pragma unroll 4
  for (int tt = 0; tt < CH_; ++tt) {
    float x = ebase[(size_t)tt * E_];
    a0 += wls[tt] * x;
    a1 += wls[CH_ + tt] * x;
    a2 += wls[2 * CH_ + tt] * x;
    a3 += wls[3 * CH_ + tt] * x;
  }
  float* pdst = partial + (((size_t)tc * B_ + b) * H_) * E_ + tid;
  pdst[0] = a0;
  pdst[E_] = a1;
  pdst[2 * E_] = a2;
  pdst[3 * E_] = a3;
}

__global__ __launch_bounds__(256) void k_reduce_c(const float* __restrict__ partial,
                                                  float* __restrict__ c) {
  const int i = blockIdx.x * 256 + threadIdx.x;
  float s = 0.f;
#pragma unroll
  for (int tc = 0; tc < TC_; ++tc) s += partial[(size_t)tc * (B_ * H_ * E_) + i];
  c[i] = s;
}

// ---------------------------------------------------------------------------
__global__ __launch_bounds__(256) void k_out_part(const float* __restrict__ c,
                                                  const float* __restrict__ Wo,
                                                  float* __restrict__ p2) {
  const int b = blockIdx.x;
  const int o = blockIdx.y * 256 + threadIdx.x;
  const int kc = blockIdx.z;
  __shared__ float cS[256];
  const int he0 = kc * 256;
  cS[threadIdx.x] = c[b * (H_ * E_) + he0 + threadIdx.x];
  __syncthreads();
  float s = 0.f;
#pragma unroll 8
  for (int i = 0; i < 256; ++i) s += cS[i] * Wo[(size_t)(he0 + i) * O_ + o];
  p2[((size_t)kc * B_ + b) * O_ + o] = s;
}

__global__ __launch_bounds__(512) void k_out_fin(const float* __restrict__ p2,
                                                 const float* __restrict__ bo,
                                                 float* __restrict__ out) {
  const int b = blockIdx.x, o = threadIdx.x;
  float s = bo[o];
#pragma unroll
  for (int kc = 0; kc < 8; ++kc) s += p2[((size_t)kc * B_ + b) * O_ + o];
  out[b * O_ + o] = s;
}

// ---------------------------------------------------------------------------
extern "C" void kernel_launch(void* const* d_in, const int* in_sizes, int n_in,
                              void* d_out, int out_size, void* d_ws, size_t ws_size,
                              hipStream_t stream) {
  (void)in_sizes; (void)n_in; (void)out_size; (void)ws_size;
  const float* enc      = (const float*)d_in[0];
  // d_in[1] = enc_len : unused by the reference
  const float* dec_z    = (const float*)d_in[2];
  const float* att_prev = (const float*)d_in[3];
  const float* Wenc     = (const float*)d_in[4];
  const float* benc     = (const float*)d_in[5];
  const float* Wdec     = (const float*)d_in[6];
  const float* Watt     = (const float*)d_in[7];
  const float* conv_w   = (const float*)d_in[8];
  const float* gv       = (const float*)d_in[9];
  const float* Wo       = (const float*)d_in[10];
  const float* bo       = (const float*)d_in[11];

  float* out  = (float*)d_out;
  float* wout = out + B_ * O_;  // ws [H,B,T]

  char* wsb = (char*)d_ws;
  float* e_buf   = (float*)(wsb);              // 1,024,000 B
  char*  convpad = wsb + 1024000;              // 8,192,000 B
  char*  wbs     = wsb + 9216000;              //   524,288 B
  char*  wattb   = wsb + 9740288;              //    16,384 B
  float* addv    = (float*)(wsb + 9756672);    //    32,768 B
  float* partial = (float*)(wsb + 9789440);    // 6,553,600 B
  float* cbuf    = (float*)(wsb + 16343040);   //   131,072 B
  float* p2      = (float*)(wsb + 16474112);   //   262,144 B

  hipLaunchKernelGGL(k_addv, dim3(B_ * H_), dim3(128), 0, stream, dec_z, Wdec, benc, addv);
  hipLaunchKernelGGL(k_conv, dim3(B_ * H_, 16), dim3(256), 0, stream, att_prev, conv_w, convpad);
  hipLaunchKernelGGL(k_wprep, dim3(132), dim3(256), 0, stream, Wenc, Watt, wbs, wattb);
  hipLaunchKernelGGL(k_fused_e_mfma, dim3(1000), dim3(256), 0, stream,
                     enc, wbs, convpad, wattb, addv, gv, e_buf);
  hipLaunchKernelGGL(k_softmax, dim3(B_ * H_), dim3(256), 0, stream, e_buf, wout);
  hipLaunchKernelGGL(k_ctx, dim3(B_, TC_), dim3(512), 0, stream, enc, wout, partial);
  hipLaunchKernelGGL(k_reduce_c, dim3(B_ * H_ * E_ / 256), dim3(256), 0, stream, partial, cbuf);
  hipLaunchKernelGGL(k_out_part, dim3(B_, O_ / 256, 8), dim3(256), 0, stream, cbuf, Wo, p2);
  hipLaunchKernelGGL(k_out_fin, dim3(B_), dim3(512), 0, stream, p2, bo, out);
}